// Round 15
// baseline (251.353 us; speedup 1.0000x reference)
//
#include <hip/hip_runtime.h>
#include <hip/hip_bf16.h>
#include <stdint.h>
#include <type_traits>

typedef __bf16 bf16;
typedef __bf16 bf16x4 __attribute__((ext_vector_type(4)));
typedef __bf16 bf16x8 __attribute__((ext_vector_type(8)));
typedef short shortx4 __attribute__((ext_vector_type(4)));
typedef float floatx4 __attribute__((ext_vector_type(4)));
typedef unsigned int u32;

#define D_MODEL 1024
#define SEQ 2048
#define NHEADS 16
#define DH 64
#define BATCH 2
#define MROWS (BATCH * SEQ)  // 4096

#define XELEMS ((size_t)MROWS * D_MODEL)
#define WELEMS ((size_t)D_MODEL * D_MODEL)
#define CVT_ELEMS (XELEMS + 4 * WELEMS)

#if __has_builtin(__builtin_amdgcn_mfma_f32_16x16x16bf16_1k)
#define MFMA16_OK 1
#endif

__device__ __forceinline__ void gload_lds16(const void* g, void* l) {
  __builtin_amdgcn_global_load_lds(
      (const __attribute__((address_space(1))) u32*)g,
      (__attribute__((address_space(3))) u32*)l, 16, 0, 0);
}

// ---------------------------------------------------------------------------
// One-shot f32 -> bf16 convert of X + 4 weights (~57 MB traffic, mem-bound).
// ---------------------------------------------------------------------------
__global__ __launch_bounds__(256) void cvt_f32_bf16(
    const float* __restrict__ s0, const float* __restrict__ s1,
    const float* __restrict__ s2, const float* __restrict__ s3,
    const float* __restrict__ s4, bf16* __restrict__ dst) {
  const size_t i = ((size_t)blockIdx.x * 256 + threadIdx.x) * 8;
  const float* src;
  size_t off;
  if (i < XELEMS) {
    src = s0; off = i;
  } else {
    const size_t j = i - XELEMS;
    const int r = (int)(j / WELEMS);
    src = (r == 0) ? s1 : (r == 1) ? s2 : (r == 2) ? s3 : s4;
    off = j - (size_t)r * WELEMS;
  }
  floatx4 f0 = *(const floatx4*)&src[off];
  floatx4 f1 = *(const floatx4*)&src[off + 4];
  bf16x8 o;
#pragma unroll
  for (int j = 0; j < 4; j++) { o[j] = (bf16)f0[j]; o[4 + j] = (bf16)f1[j]; }
  *(bf16x8*)&dst[i] = o;
}

// ---------------------------------------------------------------------------
// Merged QKV GEMM (unchanged): grid.z -> Wq/Wk/Wv, 128x128, BK=64, async
// staging, XOR swizzle.  z==2: mfma(b,a)=D^T, V^T store [b][h][d][s].
// ---------------------------------------------------------------------------
__global__ __launch_bounds__(256) void gemm_qkv(
    const bf16* __restrict__ A, const bf16* __restrict__ Wq,
    const bf16* __restrict__ Wk, const bf16* __restrict__ Wv,
    bf16* __restrict__ Qo, bf16* __restrict__ Ko, bf16* __restrict__ Vto) {
  const int z = blockIdx.z;
  const bf16* W = (z == 0) ? Wq : (z == 1) ? Wk : Wv;

  __shared__ bf16 As[128 * 64];
  __shared__ bf16 Bs[128 * 64];

  const int tid = threadIdx.x;
  const int lane = tid & 63;
  const int w = tid >> 6;
  const int lo16 = lane & 15;
  const int quad = lane >> 4;
  const int wy = w >> 1, wx = w & 1;

  const int m0 = blockIdx.y * 128;
  const int n0 = blockIdx.x * 128;

  const int sl = lane >> 3;
  const int sc = ((lane & 7) ^ sl) * 8;

  const floatx4 fz = {0.f, 0.f, 0.f, 0.f};
  floatx4 acc[4][4];
#pragma unroll
  for (int i = 0; i < 4; i++)
#pragma unroll
    for (int j = 0; j < 4; j++) acc[i][j] = fz;

  auto kloop = [&](auto vt) {
    constexpr bool VT = decltype(vt)::value;
    for (int k0 = 0; k0 < 1024; k0 += 64) {
      __syncthreads();
#pragma unroll
      for (int i = 0; i < 4; i++) {
        const int seg = i * 4 + w;
        const int row = seg * 8 + sl;
        gload_lds16(&A[(size_t)(m0 + row) * 1024 + k0 + sc], &As[seg * 512]);
        gload_lds16(&W[(size_t)(n0 + row) * 1024 + k0 + sc], &Bs[seg * 512]);
      }
      __syncthreads();

#pragma unroll
      for (int kk = 0; kk < 64; kk += 32) {
        bf16x8 af[4], bfr[4];
        const int cc = (kk >> 3) + quad;
#pragma unroll
        for (int t = 0; t < 4; t++) {
          const int ra = wy * 64 + t * 16 + lo16;
          const int rb = wx * 64 + t * 16 + lo16;
          af[t]  = *(const bf16x8*)&As[ra * 64 + ((cc ^ (ra & 7)) << 3)];
          bfr[t] = *(const bf16x8*)&Bs[rb * 64 + ((cc ^ (rb & 7)) << 3)];
        }
#pragma unroll
        for (int mt = 0; mt < 4; mt++)
#pragma unroll
          for (int nt = 0; nt < 4; nt++) {
            if constexpr (VT)
              acc[mt][nt] = __builtin_amdgcn_mfma_f32_16x16x32_bf16(bfr[nt], af[mt], acc[mt][nt], 0, 0, 0);
            else
              acc[mt][nt] = __builtin_amdgcn_mfma_f32_16x16x32_bf16(af[mt], bfr[nt], acc[mt][nt], 0, 0, 0);
          }
      }
    }
  };
  if (z == 2) kloop(std::true_type{}); else kloop(std::false_type{});

  if (z < 2) {
    bf16* C = (z == 0) ? Qo : Ko;
#pragma unroll
    for (int mt = 0; mt < 4; mt++)
#pragma unroll
      for (int nt = 0; nt < 4; nt++)
#pragma unroll
        for (int r = 0; r < 4; r++) {
          const int row = m0 + wy * 64 + mt * 16 + quad * 4 + r;
          const int col = n0 + wx * 64 + nt * 16 + lo16;
          C[(size_t)row * D_MODEL + col] = (bf16)acc[mt][nt][r];
        }
  } else {
#pragma unroll
    for (int mt = 0; mt < 4; mt++)
#pragma unroll
      for (int nt = 0; nt < 4; nt++)
#pragma unroll
        for (int r = 0; r < 4; r++) {
          const int feat = n0 + wx * 64 + nt * 16 + quad * 4 + r;
          const int tok  = m0 + wy * 64 + mt * 16 + lo16;
          const int hh = feat >> 6, dd = feat & 63;
          const int bb = tok >> 11, ss = tok & 2047;
          Vto[(size_t)((bb * NHEADS + hh) * DH + dd) * SEQ + ss] = (bf16)acc[mt][nt][r];
        }
  }
}

// ---------------------------------------------------------------------------
// O-projection GEMM (unchanged): 64x128 tile, BK=128 as two BK=64 halves,
// XOR swizzle, f32 out.
// ---------------------------------------------------------------------------
__global__ __launch_bounds__(256) void gemm_o(
    const bf16* __restrict__ A, const bf16* __restrict__ W,
    float* __restrict__ C) {
  __shared__ bf16 As[2 * 64 * 64];
  __shared__ bf16 Bs[2 * 128 * 64];

  const int tid = threadIdx.x;
  const int lane = tid & 63;
  const int w = tid >> 6;
  const int lo16 = lane & 15;
  const int quad = lane >> 4;
  const int wy = w >> 1, wx = w & 1;

  const int m0 = blockIdx.y * 64;
  const int n0 = blockIdx.x * 128;

  const int sl = lane >> 3;
  const int sc = ((lane & 7) ^ sl) * 8;

  const floatx4 fz = {0.f, 0.f, 0.f, 0.f};
  floatx4 acc[2][4];
#pragma unroll
  for (int i = 0; i < 2; i++)
#pragma unroll
    for (int j = 0; j < 4; j++) acc[i][j] = fz;

  for (int k0 = 0; k0 < 1024; k0 += 128) {
    __syncthreads();
#pragma unroll
    for (int kh = 0; kh < 2; kh++) {
#pragma unroll
      for (int i = 0; i < 2; i++) {
        const int seg = i * 4 + w;
        const int row = seg * 8 + sl;
        gload_lds16(&A[(size_t)(m0 + row) * 1024 + k0 + kh * 64 + sc],
                    &As[kh * 4096 + seg * 512]);
      }
#pragma unroll
      for (int i = 0; i < 4; i++) {
        const int seg = i * 4 + w;
        const int row = seg * 8 + sl;
        gload_lds16(&W[(size_t)(n0 + row) * 1024 + k0 + kh * 64 + sc],
                    &Bs[kh * 8192 + seg * 512]);
      }
    }
    __syncthreads();

#pragma unroll
    for (int kk = 0; kk < 128; kk += 32) {
      const int kh = kk >> 6;
      const int cc = ((kk & 63) >> 3) + quad;
      bf16x8 af[2], bfr[4];
#pragma unroll
      for (int t = 0; t < 2; t++) {
        const int ra = wy * 32 + t * 16 + lo16;
        af[t] = *(const bf16x8*)&As[kh * 4096 + ra * 64 + ((cc ^ (ra & 7)) << 3)];
      }
#pragma unroll
      for (int t = 0; t < 4; t++) {
        const int rb = wx * 64 + t * 16 + lo16;
        bfr[t] = *(const bf16x8*)&Bs[kh * 8192 + rb * 64 + ((cc ^ (rb & 7)) << 3)];
      }
#pragma unroll
      for (int mt = 0; mt < 2; mt++)
#pragma unroll
        for (int nt = 0; nt < 4; nt++)
          acc[mt][nt] = __builtin_amdgcn_mfma_f32_16x16x32_bf16(af[mt], bfr[nt], acc[mt][nt], 0, 0, 0);
    }
  }

#pragma unroll
  for (int mt = 0; mt < 2; mt++)
#pragma unroll
    for (int nt = 0; nt < 4; nt++)
#pragma unroll
      for (int r = 0; r < 4; r++) {
        const int row = m0 + wy * 32 + mt * 16 + quad * 4 + r;
        const int col = n0 + wx * 64 + nt * 16 + lo16;
        C[(size_t)row * D_MODEL + col] = acc[mt][nt][r];
      }
}

// ---------------------------------------------------------------------------
// Causal flash attention v8: v7 (512 thr, KV-chunk 128, folded pairs,
// register-prefetch staging, S^T MFMA, exp2 static-shift) with the P LDS
// bridge ELIMINATED: the S^T C-layout (col=q, row=quad*4+r=kv) is exactly
// the K=16 MFMA A-operand layout, so exp(S) feeds PV directly in registers
// via v_mfma_f32_16x16x16_bf16 (4 d-strips + 1 l-column per 16-kv strip).
// Fallback to the v7 bridge if the builtin is unavailable.
// ---------------------------------------------------------------------------
#define LPK 72    // Ks row stride (bf16): 128 rows
#define LPV 136   // VTs row stride (bf16): 64 rows x 128 kv cols
#define LPP 72    // Ps row stride (fallback only)

__global__ __launch_bounds__(512, 4) void attn_causal(
    const bf16* __restrict__ Q, const bf16* __restrict__ Kg,
    const bf16* __restrict__ Vt, bf16* __restrict__ O) {
  __shared__ __align__(16) char smem[54272];
  bf16* Ks  = (bf16*)smem;              // 128*72*2  = 18432 B
  bf16* VTs = (bf16*)(smem + 18432);    // 64*136*2  = 17408 B
  bf16* Ps  = (bf16*)(smem + 35840);    // fallback bridge: 8*16*72*2
  float* Es = (float*)smem;             // epilogue alias: 4*64*40*4 = 40960 B

  const int tid = threadIdx.x;
  const int lane = tid & 63;
  const int wid = tid >> 6;      // 0..7
  const int g = wid >> 2;        // kv-half of the 128-chunk
  const int w4 = wid & 3;        // q-quarter
  const int lo16 = lane & 15;
  const int quad = lane >> 4;

  const int x = blockIdx.x;      // 0..15
  const int qtA = x;
  const int qtB = 31 - x;
  const int nA = (qtA + 2) >> 1;
  const int nB = (qtB + 2) >> 1;
  const int h = blockIdx.y;
  const int b = blockIdx.z;
  const size_t base  = (size_t)b * SEQ * D_MODEL + (size_t)h * DH;
  const size_t baset = (size_t)(b * NHEADS + h) * DH * SEQ;

  const int rA = qtA * 64 + w4 * 16 + lo16;
  const int rB = qtB * 64 + w4 * 16 + lo16;
  bf16x8 qfA[2], qfB[2];
#pragma unroll
  for (int ks = 0; ks < 2; ks++) {
    qfA[ks] = *(const bf16x8*)&Q[base + (size_t)rA * D_MODEL + ks * 32 + quad * 8];
    qfB[ks] = *(const bf16x8*)&Q[base + (size_t)rB * D_MODEL + ks * 32 + quad * 8];
  }

#ifdef MFMA16_OK
  bf16x4 ones4;
#pragma unroll
  for (int j = 0; j < 4; j++) ones4[j] = (bf16)1.0f;
  const shortx4 ones4s = *(const shortx4*)&ones4;
#else
  bf16x8 onesf;
#pragma unroll
  for (int j = 0; j < 8; j++) onesf[j] = (bf16)1.0f;
#endif

  const floatx4 fz = {0.f, 0.f, 0.f, 0.f};
  floatx4 oA[4], oB[4];
  floatx4 lA = fz, lB = fz;
#pragma unroll
  for (int i = 0; i < 4; i++) { oA[i] = fz; oB[i] = fz; }

  const int kr = tid >> 3;        // 0..63
  const int kc = (tid & 7) * 8;

  bf16x8 kvp[2], vvp[2];
#pragma unroll
  for (int c2 = 0; c2 < 2; c2++) {
    kvp[c2] = *(const bf16x8*)&Kg[base + (size_t)(c2 * 64 + kr) * D_MODEL + kc];
    vvp[c2] = *(const bf16x8*)&Vt[baset + (size_t)kr * SEQ + c2 * 64 + kc];
  }

  for (int c = 0; c < nB; c++) {
    const int j0 = c * 128;
    __syncthreads();
#pragma unroll
    for (int c2 = 0; c2 < 2; c2++) {
      *(bf16x8*)&Ks[(c2 * 64 + kr) * LPK + kc] = kvp[c2];
      *(bf16x8*)&VTs[kr * LPV + c2 * 64 + kc] = vvp[c2];
    }
    __syncthreads();

    if (c + 1 < nB) {
      const int j1 = j0 + 128;
#pragma unroll
      for (int c2 = 0; c2 < 2; c2++) {
        kvp[c2] = *(const bf16x8*)&Kg[base + (size_t)(j1 + c2 * 64 + kr) * D_MODEL + kc];
        vvp[c2] = *(const bf16x8*)&Vt[baset + (size_t)kr * SEQ + j1 + c2 * 64 + kc];
      }
    }

#ifdef MFMA16_OK
    // hoisted V fragments for K=16 PV: B[n=d(lo16)][k=kv(quad*4+j)]
    shortx4 vf4[4][4];  // [nt][dt]
#pragma unroll
    for (int nt = 0; nt < 4; nt++)
#pragma unroll
      for (int dt = 0; dt < 4; dt++)
        vf4[nt][dt] = *(const shortx4*)&VTs[(dt * 16 + lo16) * LPV + g * 64 + nt * 16 + quad * 4];
#endif

    auto compute = [&](int q0s, const bf16x8* qf, floatx4* oacc, floatx4& lacc,
                       bool diag) {
      floatx4 sacc[4];
#pragma unroll
      for (int n = 0; n < 4; n++) sacc[n] = fz;
#pragma unroll
      for (int n = 0; n < 4; n++) {
        const int rk = g * 64 + n * 16 + lo16;
#pragma unroll
        for (int ks = 0; ks < 2; ks++) {
          bf16x8 kf = *(const bf16x8*)&Ks[rk * LPK + ks * 32 + quad * 8];
          sacc[n] = __builtin_amdgcn_mfma_f32_16x16x32_bf16(kf, qf[ks], sacc[n], 0, 0, 0);
        }
      }

#ifdef MFMA16_OK
      // p = exp(s/8 - 12) = 2^(s*0.18033688 - 17.3123405); register-direct PV
      const int myq = q0s + w4 * 16 + lo16;
#pragma unroll
      for (int n = 0; n < 4; n++) {
        bf16x4 pk;
        if (diag) {
          const int kvb = j0 + g * 64 + n * 16 + quad * 4;
#pragma unroll
          for (int r = 0; r < 4; r++) {
            const float e = __builtin_amdgcn_exp2f(fmaf(sacc[n][r], 0.18033688f, -17.3123405f));
            pk[r] = (bf16)((kvb + r > myq) ? 0.f : e);
          }
        } else {
#pragma unroll
          for (int r = 0; r < 4; r++)
            pk[r] = (bf16)__builtin_amdgcn_exp2f(fmaf(sacc[n][r], 0.18033688f, -17.3123405f));
        }
        const shortx4 pks = *(const shortx4*)&pk;
#pragma unroll
        for (int dt = 0; dt < 4; dt++)
          oacc[dt] = __builtin_amdgcn_mfma_f32_16x16x16bf16_1k(pks, vf4[n][dt], oacc[dt], 0, 0, 0);
        lacc = __builtin_amdgcn_mfma_f32_16x16x16bf16_1k(pks, ones4s, lacc, 0, 0, 0);
      }
#else
      // fallback: v7 LDS bridge
      if (diag) {
        const int myq = q0s + w4 * 16 + lo16;
#pragma unroll
        for (int n = 0; n < 4; n++) {
          const int kvb = j0 + g * 64 + n * 16 + quad * 4;
          bf16x4 pk;
#pragma unroll
          for (int r = 0; r < 4; r++) {
            const float e = __builtin_amdgcn_exp2f(fmaf(sacc[n][r], 0.18033688f, -17.3123405f));
            pk[r] = (bf16)((kvb + r > myq) ? 0.f : e);
          }
          *(bf16x4*)&Ps[wid * 1152 + lo16 * LPP + n * 16 + quad * 4] = pk;
        }
      } else {
#pragma unroll
        for (int n = 0; n < 4; n++) {
          bf16x4 pk;
#pragma unroll
          for (int r = 0; r < 4; r++)
            pk[r] = (bf16)__builtin_amdgcn_exp2f(fmaf(sacc[n][r], 0.18033688f, -17.3123405f));
          *(bf16x4*)&Ps[wid * 1152 + lo16 * LPP + n * 16 + quad * 4] = pk;
        }
      }
#pragma unroll
      for (int ks = 0; ks < 2; ks++) {
        bf16x8 pf = *(const bf16x8*)&Ps[wid * 1152 + lo16 * LPP + ks * 32 + quad * 8];
#pragma unroll
        for (int dt = 0; dt < 4; dt++) {
          bf16x8 vf = *(const bf16x8*)&VTs[(dt * 16 + lo16) * LPV + g * 64 + ks * 32 + quad * 8];
          oacc[dt] = __builtin_amdgcn_mfma_f32_16x16x32_bf16(pf, vf, oacc[dt], 0, 0, 0);
        }
        lacc = __builtin_amdgcn_mfma_f32_16x16x32_bf16(pf, onesf, lacc, 0, 0, 0);
      }
#endif
    };

    compute(qtB * 64, qfB, oB, lB, c == nB - 1);
    if (c < nA) compute(qtA * 64, qfA, oA, lA, c == nA - 1);
  }

  // epilogue: combine kv-half partials (additive; fixed shift). Es aliases
  // the staging LDS, so drain loop-phase LDS use first.
  __syncthreads();
  if (g == 1) {
    float* e = &Es[(w4 * 64 + lane) * 40];
#pragma unroll
    for (int dt = 0; dt < 4; dt++)
#pragma unroll
      for (int r = 0; r < 4; r++) e[dt * 4 + r] = oA[dt][r];
#pragma unroll
    for (int r = 0; r < 4; r++) e[16 + r] = lA[r];
#pragma unroll
    for (int dt = 0; dt < 4; dt++)
#pragma unroll
      for (int r = 0; r < 4; r++) e[20 + dt * 4 + r] = oB[dt][r];
#pragma unroll
    for (int r = 0; r < 4; r++) e[36 + r] = lB[r];
  }
  __syncthreads();
  if (g == 0) {
    const float* e = &Es[(w4 * 64 + lane) * 40];
#pragma unroll
    for (int dt = 0; dt < 4; dt++)
#pragma unroll
      for (int r = 0; r < 4; r++) { oA[dt][r] += e[dt * 4 + r]; oB[dt][r] += e[20 + dt * 4 + r]; }
#pragma unroll
    for (int r = 0; r < 4; r++) { lA[r] += e[16 + r]; lB[r] += e[36 + r]; }

    auto finish = [&](int q0s, floatx4* oacc, floatx4 lacc) {
#pragma unroll
      for (int r = 0; r < 4; r++) {
        const float inv = 1.0f / lacc[r];
        const int row = q0s + w4 * 16 + quad * 4 + r;
#pragma unroll
        for (int dt = 0; dt < 4; dt++)
          O[base + (size_t)row * D_MODEL + dt * 16 + lo16] = (bf16)(oacc[dt][r] * inv);
      }
    };
    finish(qtA * 64, oA, lA);
    finish(qtB * 64, oB, lB);
  }
}

extern "C" void kernel_launch(void* const* d_in, const int* in_sizes, int n_in,
                              void* d_out, int out_size, void* d_ws, size_t ws_size,
                              hipStream_t stream) {
  const float* X  = (const float*)d_in[0];
  const float* Wq = (const float*)d_in[1];
  const float* Wk = (const float*)d_in[2];
  const float* Wv = (const float*)d_in[3];
  const float* Wo = (const float*)d_in[4];
  float* out = (float*)d_out;

  bf16* cvt = (bf16*)d_ws;
  bf16* Xb  = cvt;
  bf16* Wqb = cvt + XELEMS;
  bf16* Wkb = Wqb + WELEMS;
  bf16* Wvb = Wkb + WELEMS;
  bf16* Wob = Wvb + WELEMS;
  bf16* Qb  = cvt + CVT_ELEMS;
  bf16* Kb  = Qb + XELEMS;
  bf16* Vtb = Kb + XELEMS;      // [B][H][DH][SEQ]
  bf16* Ob  = Vtb + XELEMS;

  dim3 blk(256);
  cvt_f32_bf16<<<dim3((u32)(CVT_ELEMS / (256 * 8))), blk, 0, stream>>>(
      X, Wq, Wk, Wv, Wo, cvt);
  gemm_qkv<<<dim3(8, 32, 3), blk, 0, stream>>>(Xb, Wqb, Wkb, Wvb, Qb, Kb, Vtb);
  attn_causal<<<dim3(16, NHEADS, BATCH), dim3(512), 0, stream>>>(Qb, Kb, Vtb, Ob);
  gemm_o<<<dim3(8, 64), blk, 0, stream>>>(Ob, Wob, out);
}

// Round 16
// 183.469 us; speedup vs baseline: 1.3700x; 1.3700x over previous
//
#include <hip/hip_runtime.h>
#include <hip/hip_bf16.h>
#include <stdint.h>
#include <type_traits>

typedef __bf16 bf16;
typedef __bf16 bf16x4 __attribute__((ext_vector_type(4)));
typedef __bf16 bf16x8 __attribute__((ext_vector_type(8)));
typedef short shortx4 __attribute__((ext_vector_type(4)));
typedef float floatx4 __attribute__((ext_vector_type(4)));
typedef unsigned int u32;

#define D_MODEL 1024
#define SEQ 2048
#define NHEADS 16
#define DH 64
#define BATCH 2
#define MROWS (BATCH * SEQ)  // 4096

#define XELEMS ((size_t)MROWS * D_MODEL)
#define WELEMS ((size_t)D_MODEL * D_MODEL)
#define CVT_ELEMS (XELEMS + 4 * WELEMS)

#if __has_builtin(__builtin_amdgcn_mfma_f32_16x16x16bf16_1k)
#define MFMA16_OK 1
#endif

__device__ __forceinline__ void gload_lds16(const void* g, void* l) {
  __builtin_amdgcn_global_load_lds(
      (const __attribute__((address_space(1))) u32*)g,
      (__attribute__((address_space(3))) u32*)l, 16, 0, 0);
}

// ---------------------------------------------------------------------------
// One-shot f32 -> bf16 convert of X + 4 weights (~57 MB traffic, mem-bound).
// ---------------------------------------------------------------------------
__global__ __launch_bounds__(256) void cvt_f32_bf16(
    const float* __restrict__ s0, const float* __restrict__ s1,
    const float* __restrict__ s2, const float* __restrict__ s3,
    const float* __restrict__ s4, bf16* __restrict__ dst) {
  const size_t i = ((size_t)blockIdx.x * 256 + threadIdx.x) * 8;
  const float* src;
  size_t off;
  if (i < XELEMS) {
    src = s0; off = i;
  } else {
    const size_t j = i - XELEMS;
    const int r = (int)(j / WELEMS);
    src = (r == 0) ? s1 : (r == 1) ? s2 : (r == 2) ? s3 : s4;
    off = j - (size_t)r * WELEMS;
  }
  floatx4 f0 = *(const floatx4*)&src[off];
  floatx4 f1 = *(const floatx4*)&src[off + 4];
  bf16x8 o;
#pragma unroll
  for (int j = 0; j < 4; j++) { o[j] = (bf16)f0[j]; o[4 + j] = (bf16)f1[j]; }
  *(bf16x8*)&dst[i] = o;
}

// ---------------------------------------------------------------------------
// Merged QKV GEMM (unchanged): grid.z -> Wq/Wk/Wv, 128x128, BK=64, async
// staging, XOR swizzle.  z==2: mfma(b,a)=D^T, V^T store [b][h][d][s].
// ---------------------------------------------------------------------------
__global__ __launch_bounds__(256) void gemm_qkv(
    const bf16* __restrict__ A, const bf16* __restrict__ Wq,
    const bf16* __restrict__ Wk, const bf16* __restrict__ Wv,
    bf16* __restrict__ Qo, bf16* __restrict__ Ko, bf16* __restrict__ Vto) {
  const int z = blockIdx.z;
  const bf16* W = (z == 0) ? Wq : (z == 1) ? Wk : Wv;

  __shared__ bf16 As[128 * 64];
  __shared__ bf16 Bs[128 * 64];

  const int tid = threadIdx.x;
  const int lane = tid & 63;
  const int w = tid >> 6;
  const int lo16 = lane & 15;
  const int quad = lane >> 4;
  const int wy = w >> 1, wx = w & 1;

  const int m0 = blockIdx.y * 128;
  const int n0 = blockIdx.x * 128;

  const int sl = lane >> 3;
  const int sc = ((lane & 7) ^ sl) * 8;

  const floatx4 fz = {0.f, 0.f, 0.f, 0.f};
  floatx4 acc[4][4];
#pragma unroll
  for (int i = 0; i < 4; i++)
#pragma unroll
    for (int j = 0; j < 4; j++) acc[i][j] = fz;

  auto kloop = [&](auto vt) {
    constexpr bool VT = decltype(vt)::value;
    for (int k0 = 0; k0 < 1024; k0 += 64) {
      __syncthreads();
#pragma unroll
      for (int i = 0; i < 4; i++) {
        const int seg = i * 4 + w;
        const int row = seg * 8 + sl;
        gload_lds16(&A[(size_t)(m0 + row) * 1024 + k0 + sc], &As[seg * 512]);
        gload_lds16(&W[(size_t)(n0 + row) * 1024 + k0 + sc], &Bs[seg * 512]);
      }
      __syncthreads();

#pragma unroll
      for (int kk = 0; kk < 64; kk += 32) {
        bf16x8 af[4], bfr[4];
        const int cc = (kk >> 3) + quad;
#pragma unroll
        for (int t = 0; t < 4; t++) {
          const int ra = wy * 64 + t * 16 + lo16;
          const int rb = wx * 64 + t * 16 + lo16;
          af[t]  = *(const bf16x8*)&As[ra * 64 + ((cc ^ (ra & 7)) << 3)];
          bfr[t] = *(const bf16x8*)&Bs[rb * 64 + ((cc ^ (rb & 7)) << 3)];
        }
#pragma unroll
        for (int mt = 0; mt < 4; mt++)
#pragma unroll
          for (int nt = 0; nt < 4; nt++) {
            if constexpr (VT)
              acc[mt][nt] = __builtin_amdgcn_mfma_f32_16x16x32_bf16(bfr[nt], af[mt], acc[mt][nt], 0, 0, 0);
            else
              acc[mt][nt] = __builtin_amdgcn_mfma_f32_16x16x32_bf16(af[mt], bfr[nt], acc[mt][nt], 0, 0, 0);
          }
      }
    }
  };
  if (z == 2) kloop(std::true_type{}); else kloop(std::false_type{});

  if (z < 2) {
    bf16* C = (z == 0) ? Qo : Ko;
#pragma unroll
    for (int mt = 0; mt < 4; mt++)
#pragma unroll
      for (int nt = 0; nt < 4; nt++)
#pragma unroll
        for (int r = 0; r < 4; r++) {
          const int row = m0 + wy * 64 + mt * 16 + quad * 4 + r;
          const int col = n0 + wx * 64 + nt * 16 + lo16;
          C[(size_t)row * D_MODEL + col] = (bf16)acc[mt][nt][r];
        }
  } else {
#pragma unroll
    for (int mt = 0; mt < 4; mt++)
#pragma unroll
      for (int nt = 0; nt < 4; nt++)
#pragma unroll
        for (int r = 0; r < 4; r++) {
          const int feat = n0 + wx * 64 + nt * 16 + quad * 4 + r;
          const int tok  = m0 + wy * 64 + mt * 16 + lo16;
          const int hh = feat >> 6, dd = feat & 63;
          const int bb = tok >> 11, ss = tok & 2047;
          Vto[(size_t)((bb * NHEADS + hh) * DH + dd) * SEQ + ss] = (bf16)acc[mt][nt][r];
        }
  }
}

// ---------------------------------------------------------------------------
// O-projection GEMM (unchanged): 64x128 tile, BK=128 as two BK=64 halves,
// XOR swizzle, f32 out.
// ---------------------------------------------------------------------------
__global__ __launch_bounds__(256) void gemm_o(
    const bf16* __restrict__ A, const bf16* __restrict__ W,
    float* __restrict__ C) {
  __shared__ bf16 As[2 * 64 * 64];
  __shared__ bf16 Bs[2 * 128 * 64];

  const int tid = threadIdx.x;
  const int lane = tid & 63;
  const int w = tid >> 6;
  const int lo16 = lane & 15;
  const int quad = lane >> 4;
  const int wy = w >> 1, wx = w & 1;

  const int m0 = blockIdx.y * 64;
  const int n0 = blockIdx.x * 128;

  const int sl = lane >> 3;
  const int sc = ((lane & 7) ^ sl) * 8;

  const floatx4 fz = {0.f, 0.f, 0.f, 0.f};
  floatx4 acc[2][4];
#pragma unroll
  for (int i = 0; i < 2; i++)
#pragma unroll
    for (int j = 0; j < 4; j++) acc[i][j] = fz;

  for (int k0 = 0; k0 < 1024; k0 += 128) {
    __syncthreads();
#pragma unroll
    for (int kh = 0; kh < 2; kh++) {
#pragma unroll
      for (int i = 0; i < 2; i++) {
        const int seg = i * 4 + w;
        const int row = seg * 8 + sl;
        gload_lds16(&A[(size_t)(m0 + row) * 1024 + k0 + kh * 64 + sc],
                    &As[kh * 4096 + seg * 512]);
      }
#pragma unroll
      for (int i = 0; i < 4; i++) {
        const int seg = i * 4 + w;
        const int row = seg * 8 + sl;
        gload_lds16(&W[(size_t)(n0 + row) * 1024 + k0 + kh * 64 + sc],
                    &Bs[kh * 8192 + seg * 512]);
      }
    }
    __syncthreads();

#pragma unroll
    for (int kk = 0; kk < 128; kk += 32) {
      const int kh = kk >> 6;
      const int cc = ((kk & 63) >> 3) + quad;
      bf16x8 af[2], bfr[4];
#pragma unroll
      for (int t = 0; t < 2; t++) {
        const int ra = wy * 32 + t * 16 + lo16;
        af[t] = *(const bf16x8*)&As[kh * 4096 + ra * 64 + ((cc ^ (ra & 7)) << 3)];
      }
#pragma unroll
      for (int t = 0; t < 4; t++) {
        const int rb = wx * 64 + t * 16 + lo16;
        bfr[t] = *(const bf16x8*)&Bs[kh * 8192 + rb * 64 + ((cc ^ (rb & 7)) << 3)];
      }
#pragma unroll
      for (int mt = 0; mt < 2; mt++)
#pragma unroll
        for (int nt = 0; nt < 4; nt++)
          acc[mt][nt] = __builtin_amdgcn_mfma_f32_16x16x32_bf16(af[mt], bfr[nt], acc[mt][nt], 0, 0, 0);
    }
  }

#pragma unroll
  for (int mt = 0; mt < 2; mt++)
#pragma unroll
    for (int nt = 0; nt < 4; nt++)
#pragma unroll
      for (int r = 0; r < 4; r++) {
        const int row = m0 + wy * 32 + mt * 16 + quad * 4 + r;
        const int col = n0 + wx * 64 + nt * 16 + lo16;
        C[(size_t)row * D_MODEL + col] = acc[mt][nt][r];
      }
}

// ---------------------------------------------------------------------------
// Causal flash attention v8b: register-direct PV via K=16 MFMA (S^T C-layout
// == K=16 A-layout), with the round-15 spill bug fixed:
//  - __launch_bounds__(512, 2): VGPR budget 128 (not 64); occupancy is
//    LDS-capped at 2 blocks/CU anyway, so nothing is lost.
//  - V fragments read per-strip inside compute (transient regs), not hoisted.
// ---------------------------------------------------------------------------
#define LPK 72    // Ks row stride (bf16): 128 rows
#define LPV 136   // VTs row stride (bf16): 64 rows x 128 kv cols
#define LPP 72    // Ps row stride (fallback only)

__global__ __launch_bounds__(512, 2) void attn_causal(
    const bf16* __restrict__ Q, const bf16* __restrict__ Kg,
    const bf16* __restrict__ Vt, bf16* __restrict__ O) {
  __shared__ __align__(16) char smem[54272];
  bf16* Ks  = (bf16*)smem;              // 128*72*2  = 18432 B
  bf16* VTs = (bf16*)(smem + 18432);    // 64*136*2  = 17408 B
  bf16* Ps  = (bf16*)(smem + 35840);    // fallback bridge: 8*16*72*2
  float* Es = (float*)smem;             // epilogue alias: 4*64*40*4 = 40960 B

  const int tid = threadIdx.x;
  const int lane = tid & 63;
  const int wid = tid >> 6;      // 0..7
  const int g = wid >> 2;        // kv-half of the 128-chunk
  const int w4 = wid & 3;        // q-quarter
  const int lo16 = lane & 15;
  const int quad = lane >> 4;

  const int x = blockIdx.x;      // 0..15
  const int qtA = x;
  const int qtB = 31 - x;
  const int nA = (qtA + 2) >> 1;
  const int nB = (qtB + 2) >> 1;
  const int h = blockIdx.y;
  const int b = blockIdx.z;
  const size_t base  = (size_t)b * SEQ * D_MODEL + (size_t)h * DH;
  const size_t baset = (size_t)(b * NHEADS + h) * DH * SEQ;

  const int rA = qtA * 64 + w4 * 16 + lo16;
  const int rB = qtB * 64 + w4 * 16 + lo16;
  bf16x8 qfA[2], qfB[2];
#pragma unroll
  for (int ks = 0; ks < 2; ks++) {
    qfA[ks] = *(const bf16x8*)&Q[base + (size_t)rA * D_MODEL + ks * 32 + quad * 8];
    qfB[ks] = *(const bf16x8*)&Q[base + (size_t)rB * D_MODEL + ks * 32 + quad * 8];
  }

#ifdef MFMA16_OK
  bf16x4 ones4;
#pragma unroll
  for (int j = 0; j < 4; j++) ones4[j] = (bf16)1.0f;
  const shortx4 ones4s = *(const shortx4*)&ones4;
#else
  bf16x8 onesf;
#pragma unroll
  for (int j = 0; j < 8; j++) onesf[j] = (bf16)1.0f;
#endif

  const floatx4 fz = {0.f, 0.f, 0.f, 0.f};
  floatx4 oA[4], oB[4];
  floatx4 lA = fz, lB = fz;
#pragma unroll
  for (int i = 0; i < 4; i++) { oA[i] = fz; oB[i] = fz; }

  const int kr = tid >> 3;        // 0..63
  const int kc = (tid & 7) * 8;

  bf16x8 kvp[2], vvp[2];
#pragma unroll
  for (int c2 = 0; c2 < 2; c2++) {
    kvp[c2] = *(const bf16x8*)&Kg[base + (size_t)(c2 * 64 + kr) * D_MODEL + kc];
    vvp[c2] = *(const bf16x8*)&Vt[baset + (size_t)kr * SEQ + c2 * 64 + kc];
  }

  for (int c = 0; c < nB; c++) {
    const int j0 = c * 128;
    __syncthreads();
#pragma unroll
    for (int c2 = 0; c2 < 2; c2++) {
      *(bf16x8*)&Ks[(c2 * 64 + kr) * LPK + kc] = kvp[c2];
      *(bf16x8*)&VTs[kr * LPV + c2 * 64 + kc] = vvp[c2];
    }
    __syncthreads();

    if (c + 1 < nB) {
      const int j1 = j0 + 128;
#pragma unroll
      for (int c2 = 0; c2 < 2; c2++) {
        kvp[c2] = *(const bf16x8*)&Kg[base + (size_t)(j1 + c2 * 64 + kr) * D_MODEL + kc];
        vvp[c2] = *(const bf16x8*)&Vt[baset + (size_t)kr * SEQ + j1 + c2 * 64 + kc];
      }
    }

    auto compute = [&](int q0s, const bf16x8* qf, floatx4* oacc, floatx4& lacc,
                       bool diag) {
      floatx4 sacc[4];
#pragma unroll
      for (int n = 0; n < 4; n++) sacc[n] = fz;
#pragma unroll
      for (int n = 0; n < 4; n++) {
        const int rk = g * 64 + n * 16 + lo16;
#pragma unroll
        for (int ks = 0; ks < 2; ks++) {
          bf16x8 kf = *(const bf16x8*)&Ks[rk * LPK + ks * 32 + quad * 8];
          sacc[n] = __builtin_amdgcn_mfma_f32_16x16x32_bf16(kf, qf[ks], sacc[n], 0, 0, 0);
        }
      }

#ifdef MFMA16_OK
      // p = exp(s/8 - 12) = 2^(s*0.18033688 - 17.3123405); register-direct PV
      const int myq = q0s + w4 * 16 + lo16;
#pragma unroll
      for (int n = 0; n < 4; n++) {
        bf16x4 pk;
        if (diag) {
          const int kvb = j0 + g * 64 + n * 16 + quad * 4;
#pragma unroll
          for (int r = 0; r < 4; r++) {
            const float e = __builtin_amdgcn_exp2f(fmaf(sacc[n][r], 0.18033688f, -17.3123405f));
            pk[r] = (bf16)((kvb + r > myq) ? 0.f : e);
          }
        } else {
#pragma unroll
          for (int r = 0; r < 4; r++)
            pk[r] = (bf16)__builtin_amdgcn_exp2f(fmaf(sacc[n][r], 0.18033688f, -17.3123405f));
        }
        const shortx4 pks = *(const shortx4*)&pk;
#pragma unroll
        for (int dt = 0; dt < 4; dt++) {
          const shortx4 vf = *(const shortx4*)&VTs[(dt * 16 + lo16) * LPV + g * 64 + n * 16 + quad * 4];
          oacc[dt] = __builtin_amdgcn_mfma_f32_16x16x16bf16_1k(pks, vf, oacc[dt], 0, 0, 0);
        }
        lacc = __builtin_amdgcn_mfma_f32_16x16x16bf16_1k(pks, ones4s, lacc, 0, 0, 0);
      }
#else
      // fallback: LDS bridge
      if (diag) {
        const int myq = q0s + w4 * 16 + lo16;
#pragma unroll
        for (int n = 0; n < 4; n++) {
          const int kvb = j0 + g * 64 + n * 16 + quad * 4;
          bf16x4 pk;
#pragma unroll
          for (int r = 0; r < 4; r++) {
            const float e = __builtin_amdgcn_exp2f(fmaf(sacc[n][r], 0.18033688f, -17.3123405f));
            pk[r] = (bf16)((kvb + r > myq) ? 0.f : e);
          }
          *(bf16x4*)&Ps[wid * 1152 + lo16 * LPP + n * 16 + quad * 4] = pk;
        }
      } else {
#pragma unroll
        for (int n = 0; n < 4; n++) {
          bf16x4 pk;
#pragma unroll
          for (int r = 0; r < 4; r++)
            pk[r] = (bf16)__builtin_amdgcn_exp2f(fmaf(sacc[n][r], 0.18033688f, -17.3123405f));
          *(bf16x4*)&Ps[wid * 1152 + lo16 * LPP + n * 16 + quad * 4] = pk;
        }
      }
#pragma unroll
      for (int ks = 0; ks < 2; ks++) {
        bf16x8 pf = *(const bf16x8*)&Ps[wid * 1152 + lo16 * LPP + ks * 32 + quad * 8];
#pragma unroll
        for (int dt = 0; dt < 4; dt++) {
          bf16x8 vf = *(const bf16x8*)&VTs[(dt * 16 + lo16) * LPV + g * 64 + ks * 32 + quad * 8];
          oacc[dt] = __builtin_amdgcn_mfma_f32_16x16x32_bf16(pf, vf, oacc[dt], 0, 0, 0);
        }
        lacc = __builtin_amdgcn_mfma_f32_16x16x32_bf16(pf, onesf, lacc, 0, 0, 0);
      }
#endif
    };

    compute(qtB * 64, qfB, oB, lB, c == nB - 1);
    if (c < nA) compute(qtA * 64, qfA, oA, lA, c == nA - 1);
  }

  // epilogue: combine kv-half partials (additive; fixed shift). Es aliases
  // the staging LDS, so drain loop-phase LDS use first.
  __syncthreads();
  if (g == 1) {
    float* e = &Es[(w4 * 64 + lane) * 40];
#pragma unroll
    for (int dt = 0; dt < 4; dt++)
#pragma unroll
      for (int r = 0; r < 4; r++) e[dt * 4 + r] = oA[dt][r];
#pragma unroll
    for (int r = 0; r < 4; r++) e[16 + r] = lA[r];
#pragma unroll
    for (int dt = 0; dt < 4; dt++)
#pragma unroll
      for (int r = 0; r < 4; r++) e[20 + dt * 4 + r] = oB[dt][r];
#pragma unroll
    for (int r = 0; r < 4; r++) e[36 + r] = lB[r];
  }
  __syncthreads();
  if (g == 0) {
    const float* e = &Es[(w4 * 64 + lane) * 40];
#pragma unroll
    for (int dt = 0; dt < 4; dt++)
#pragma unroll
      for (int r = 0; r < 4; r++) { oA[dt][r] += e[dt * 4 + r]; oB[dt][r] += e[20 + dt * 4 + r]; }
#pragma unroll
    for (int r = 0; r < 4; r++) { lA[r] += e[16 + r]; lB[r] += e[36 + r]; }

    auto finish = [&](int q0s, floatx4* oacc, floatx4 lacc) {
#pragma unroll
      for (int r = 0; r < 4; r++) {
        const float inv = 1.0f / lacc[r];
        const int row = q0s + w4 * 16 + quad * 4 + r;
#pragma unroll
        for (int dt = 0; dt < 4; dt++)
          O[base + (size_t)row * D_MODEL + dt * 16 + lo16] = (bf16)(oacc[dt][r] * inv);
      }
    };
    finish(qtA * 64, oA, lA);
    finish(qtB * 64, oB, lB);
  }
}

extern "C" void kernel_launch(void* const* d_in, const int* in_sizes, int n_in,
                              void* d_out, int out_size, void* d_ws, size_t ws_size,
                              hipStream_t stream) {
  const float* X  = (const float*)d_in[0];
  const float* Wq = (const float*)d_in[1];
  const float* Wk = (const float*)d_in[2];
  const float* Wv = (const float*)d_in[3];
  const float* Wo = (const float*)d_in[4];
  float* out = (float*)d_out;

  bf16* cvt = (bf16*)d_ws;
  bf16* Xb  = cvt;
  bf16* Wqb = cvt + XELEMS;
  bf16* Wkb = Wqb + WELEMS;
  bf16* Wvb = Wkb + WELEMS;
  bf16* Wob = Wvb + WELEMS;
  bf16* Qb  = cvt + CVT_ELEMS;
  bf16* Kb  = Qb + XELEMS;
  bf16* Vtb = Kb + XELEMS;      // [B][H][DH][SEQ]
  bf16* Ob  = Vtb + XELEMS;

  dim3 blk(256);
  cvt_f32_bf16<<<dim3((u32)(CVT_ELEMS / (256 * 8))), blk, 0, stream>>>(
      X, Wq, Wk, Wv, Wo, cvt);
  gemm_qkv<<<dim3(8, 32, 3), blk, 0, stream>>>(Xb, Wqb, Wkb, Wvb, Qb, Kb, Vtb);
  attn_causal<<<dim3(16, NHEADS, BATCH), dim3(512), 0, stream>>>(Qb, Kb, Vtb, Ob);
  gemm_o<<<dim3(8, 64), blk, 0, stream>>>(Ob, Wob, out);
}

// Round 17
// 181.628 us; speedup vs baseline: 1.3839x; 1.0101x over previous
//
#include <hip/hip_runtime.h>
#include <hip/hip_bf16.h>
#include <stdint.h>
#include <type_traits>

typedef __bf16 bf16;
typedef __bf16 bf16x4 __attribute__((ext_vector_type(4)));
typedef __bf16 bf16x8 __attribute__((ext_vector_type(8)));
typedef float floatx4 __attribute__((ext_vector_type(4)));
typedef unsigned int u32;

#define D_MODEL 1024
#define SEQ 2048
#define NHEADS 16
#define DH 64
#define BATCH 2
#define MROWS (BATCH * SEQ)  // 4096

#define XELEMS ((size_t)MROWS * D_MODEL)
#define WELEMS ((size_t)D_MODEL * D_MODEL)
#define CVT_ELEMS (XELEMS + 4 * WELEMS)

__device__ __forceinline__ void gload_lds16(const void* g, void* l) {
  __builtin_amdgcn_global_load_lds(
      (const __attribute__((address_space(1))) u32*)g,
      (__attribute__((address_space(3))) u32*)l, 16, 0, 0);
}

// ---------------------------------------------------------------------------
// One-shot f32 -> bf16 convert of X + 4 weights (~57 MB traffic, mem-bound).
// ---------------------------------------------------------------------------
__global__ __launch_bounds__(256) void cvt_f32_bf16(
    const float* __restrict__ s0, const float* __restrict__ s1,
    const float* __restrict__ s2, const float* __restrict__ s3,
    const float* __restrict__ s4, bf16* __restrict__ dst) {
  const size_t i = ((size_t)blockIdx.x * 256 + threadIdx.x) * 8;
  const float* src;
  size_t off;
  if (i < XELEMS) {
    src = s0; off = i;
  } else {
    const size_t j = i - XELEMS;
    const int r = (int)(j / WELEMS);
    src = (r == 0) ? s1 : (r == 1) ? s2 : (r == 2) ? s3 : s4;
    off = j - (size_t)r * WELEMS;
  }
  floatx4 f0 = *(const floatx4*)&src[off];
  floatx4 f1 = *(const floatx4*)&src[off + 4];
  bf16x8 o;
#pragma unroll
  for (int j = 0; j < 4; j++) { o[j] = (bf16)f0[j]; o[4 + j] = (bf16)f1[j]; }
  *(bf16x8*)&dst[i] = o;
}

// ---------------------------------------------------------------------------
// Merged QKV GEMM (unchanged): grid.z -> Wq/Wk/Wv, 128x128, BK=64, async
// staging, XOR swizzle.  z==2: mfma(b,a)=D^T, V^T store [b][h][d][s].
// ---------------------------------------------------------------------------
__global__ __launch_bounds__(256) void gemm_qkv(
    const bf16* __restrict__ A, const bf16* __restrict__ Wq,
    const bf16* __restrict__ Wk, const bf16* __restrict__ Wv,
    bf16* __restrict__ Qo, bf16* __restrict__ Ko, bf16* __restrict__ Vto) {
  const int z = blockIdx.z;
  const bf16* W = (z == 0) ? Wq : (z == 1) ? Wk : Wv;

  __shared__ bf16 As[128 * 64];
  __shared__ bf16 Bs[128 * 64];

  const int tid = threadIdx.x;
  const int lane = tid & 63;
  const int w = tid >> 6;
  const int lo16 = lane & 15;
  const int quad = lane >> 4;
  const int wy = w >> 1, wx = w & 1;

  const int m0 = blockIdx.y * 128;
  const int n0 = blockIdx.x * 128;

  const int sl = lane >> 3;
  const int sc = ((lane & 7) ^ sl) * 8;

  const floatx4 fz = {0.f, 0.f, 0.f, 0.f};
  floatx4 acc[4][4];
#pragma unroll
  for (int i = 0; i < 4; i++)
#pragma unroll
    for (int j = 0; j < 4; j++) acc[i][j] = fz;

  auto kloop = [&](auto vt) {
    constexpr bool VT = decltype(vt)::value;
    for (int k0 = 0; k0 < 1024; k0 += 64) {
      __syncthreads();
#pragma unroll
      for (int i = 0; i < 4; i++) {
        const int seg = i * 4 + w;
        const int row = seg * 8 + sl;
        gload_lds16(&A[(size_t)(m0 + row) * 1024 + k0 + sc], &As[seg * 512]);
        gload_lds16(&W[(size_t)(n0 + row) * 1024 + k0 + sc], &Bs[seg * 512]);
      }
      __syncthreads();

#pragma unroll
      for (int kk = 0; kk < 64; kk += 32) {
        bf16x8 af[4], bfr[4];
        const int cc = (kk >> 3) + quad;
#pragma unroll
        for (int t = 0; t < 4; t++) {
          const int ra = wy * 64 + t * 16 + lo16;
          const int rb = wx * 64 + t * 16 + lo16;
          af[t]  = *(const bf16x8*)&As[ra * 64 + ((cc ^ (ra & 7)) << 3)];
          bfr[t] = *(const bf16x8*)&Bs[rb * 64 + ((cc ^ (rb & 7)) << 3)];
        }
#pragma unroll
        for (int mt = 0; mt < 4; mt++)
#pragma unroll
          for (int nt = 0; nt < 4; nt++) {
            if constexpr (VT)
              acc[mt][nt] = __builtin_amdgcn_mfma_f32_16x16x32_bf16(bfr[nt], af[mt], acc[mt][nt], 0, 0, 0);
            else
              acc[mt][nt] = __builtin_amdgcn_mfma_f32_16x16x32_bf16(af[mt], bfr[nt], acc[mt][nt], 0, 0, 0);
          }
      }
    }
  };
  if (z == 2) kloop(std::true_type{}); else kloop(std::false_type{});

  if (z < 2) {
    bf16* C = (z == 0) ? Qo : Ko;
#pragma unroll
    for (int mt = 0; mt < 4; mt++)
#pragma unroll
      for (int nt = 0; nt < 4; nt++)
#pragma unroll
        for (int r = 0; r < 4; r++) {
          const int row = m0 + wy * 64 + mt * 16 + quad * 4 + r;
          const int col = n0 + wx * 64 + nt * 16 + lo16;
          C[(size_t)row * D_MODEL + col] = (bf16)acc[mt][nt][r];
        }
  } else {
#pragma unroll
    for (int mt = 0; mt < 4; mt++)
#pragma unroll
      for (int nt = 0; nt < 4; nt++)
#pragma unroll
        for (int r = 0; r < 4; r++) {
          const int feat = n0 + wx * 64 + nt * 16 + quad * 4 + r;
          const int tok  = m0 + wy * 64 + mt * 16 + lo16;
          const int hh = feat >> 6, dd = feat & 63;
          const int bb = tok >> 11, ss = tok & 2047;
          Vto[(size_t)((bb * NHEADS + hh) * DH + dd) * SEQ + ss] = (bf16)acc[mt][nt][r];
        }
  }
}

// ---------------------------------------------------------------------------
// O-projection GEMM (unchanged): 64x128 tile, BK=128 as two BK=64 halves,
// XOR swizzle, f32 out.
// ---------------------------------------------------------------------------
__global__ __launch_bounds__(256) void gemm_o(
    const bf16* __restrict__ A, const bf16* __restrict__ W,
    float* __restrict__ C) {
  __shared__ bf16 As[2 * 64 * 64];
  __shared__ bf16 Bs[2 * 128 * 64];

  const int tid = threadIdx.x;
  const int lane = tid & 63;
  const int w = tid >> 6;
  const int lo16 = lane & 15;
  const int quad = lane >> 4;
  const int wy = w >> 1, wx = w & 1;

  const int m0 = blockIdx.y * 64;
  const int n0 = blockIdx.x * 128;

  const int sl = lane >> 3;
  const int sc = ((lane & 7) ^ sl) * 8;

  const floatx4 fz = {0.f, 0.f, 0.f, 0.f};
  floatx4 acc[2][4];
#pragma unroll
  for (int i = 0; i < 2; i++)
#pragma unroll
    for (int j = 0; j < 4; j++) acc[i][j] = fz;

  for (int k0 = 0; k0 < 1024; k0 += 128) {
    __syncthreads();
#pragma unroll
    for (int kh = 0; kh < 2; kh++) {
#pragma unroll
      for (int i = 0; i < 2; i++) {
        const int seg = i * 4 + w;
        const int row = seg * 8 + sl;
        gload_lds16(&A[(size_t)(m0 + row) * 1024 + k0 + kh * 64 + sc],
                    &As[kh * 4096 + seg * 512]);
      }
#pragma unroll
      for (int i = 0; i < 4; i++) {
        const int seg = i * 4 + w;
        const int row = seg * 8 + sl;
        gload_lds16(&W[(size_t)(n0 + row) * 1024 + k0 + kh * 64 + sc],
                    &Bs[kh * 8192 + seg * 512]);
      }
    }
    __syncthreads();

#pragma unroll
    for (int kk = 0; kk < 128; kk += 32) {
      const int kh = kk >> 6;
      const int cc = ((kk & 63) >> 3) + quad;
      bf16x8 af[2], bfr[4];
#pragma unroll
      for (int t = 0; t < 2; t++) {
        const int ra = wy * 32 + t * 16 + lo16;
        af[t] = *(const bf16x8*)&As[kh * 4096 + ra * 64 + ((cc ^ (ra & 7)) << 3)];
      }
#pragma unroll
      for (int t = 0; t < 4; t++) {
        const int rb = wx * 64 + t * 16 + lo16;
        bfr[t] = *(const bf16x8*)&Bs[kh * 8192 + rb * 64 + ((cc ^ (rb & 7)) << 3)];
      }
#pragma unroll
      for (int mt = 0; mt < 2; mt++)
#pragma unroll
        for (int nt = 0; nt < 4; nt++)
          acc[mt][nt] = __builtin_amdgcn_mfma_f32_16x16x32_bf16(af[mt], bfr[nt], acc[mt][nt], 0, 0, 0);
    }
  }

#pragma unroll
  for (int mt = 0; mt < 2; mt++)
#pragma unroll
    for (int nt = 0; nt < 4; nt++)
#pragma unroll
      for (int r = 0; r < 4; r++) {
        const int row = m0 + wy * 32 + mt * 16 + quad * 4 + r;
        const int col = n0 + wx * 64 + nt * 16 + lo16;
        C[(size_t)row * D_MODEL + col] = acc[mt][nt][r];
      }
}

// ---------------------------------------------------------------------------
// Causal flash attention v9 = r14 v7 (KV-chunk 128, g-split, folded pairs,
// K=32 PV via LDS bridge — best measured) with two fixes from r15/r16:
//  - __launch_bounds__(512, 2): 128-VGPR budget kills v7's hidden ~22 MB
//    scratch spill (r14 WRITE_SIZE evidence); occupancy unchanged (LDS-capped
//    at 2 blocks/CU).
//  - kf fragments hoisted once per chunk, shared by both q-set computes
//    (the LDS pipe is the saturated resource; this cuts its traffic).
// ---------------------------------------------------------------------------
#define LPK 72    // Ks row stride (bf16): 128 rows
#define LPV 136   // VTs row stride (bf16): 64 rows x 128 kv cols
#define LPP 72    // Ps row stride

__global__ __launch_bounds__(512, 2) void attn_causal(
    const bf16* __restrict__ Q, const bf16* __restrict__ Kg,
    const bf16* __restrict__ Vt, bf16* __restrict__ O) {
  __shared__ __align__(16) char smem[54272];
  bf16* Ks  = (bf16*)smem;              // 128*72*2  = 18432 B
  bf16* VTs = (bf16*)(smem + 18432);    // 64*136*2  = 17408 B
  bf16* Ps  = (bf16*)(smem + 35840);    // 8*16*72*2 = 18432 B
  float* Es = (float*)smem;             // epilogue alias: 4*64*40*4 = 40960 B

  const int tid = threadIdx.x;
  const int lane = tid & 63;
  const int wid = tid >> 6;      // 0..7
  const int g = wid >> 2;        // kv-half of the 128-chunk
  const int w4 = wid & 3;        // q-quarter
  const int lo16 = lane & 15;
  const int quad = lane >> 4;

  const int x = blockIdx.x;      // 0..15
  const int qtA = x;
  const int qtB = 31 - x;
  const int nA = (qtA + 2) >> 1;
  const int nB = (qtB + 2) >> 1;
  const int h = blockIdx.y;
  const int b = blockIdx.z;
  const size_t base  = (size_t)b * SEQ * D_MODEL + (size_t)h * DH;
  const size_t baset = (size_t)(b * NHEADS + h) * DH * SEQ;

  const int rA = qtA * 64 + w4 * 16 + lo16;
  const int rB = qtB * 64 + w4 * 16 + lo16;
  bf16x8 qfA[2], qfB[2];
#pragma unroll
  for (int ks = 0; ks < 2; ks++) {
    qfA[ks] = *(const bf16x8*)&Q[base + (size_t)rA * D_MODEL + ks * 32 + quad * 8];
    qfB[ks] = *(const bf16x8*)&Q[base + (size_t)rB * D_MODEL + ks * 32 + quad * 8];
  }

  bf16x8 onesf;
#pragma unroll
  for (int j = 0; j < 8; j++) onesf[j] = (bf16)1.0f;

  const floatx4 fz = {0.f, 0.f, 0.f, 0.f};
  floatx4 oA[4], oB[4];
  floatx4 lA = fz, lB = fz;
#pragma unroll
  for (int i = 0; i < 4; i++) { oA[i] = fz; oB[i] = fz; }

  const int kr = tid >> 3;        // 0..63
  const int kc = (tid & 7) * 8;

  bf16x8 kvp[2], vvp[2];
#pragma unroll
  for (int c2 = 0; c2 < 2; c2++) {
    kvp[c2] = *(const bf16x8*)&Kg[base + (size_t)(c2 * 64 + kr) * D_MODEL + kc];
    vvp[c2] = *(const bf16x8*)&Vt[baset + (size_t)kr * SEQ + c2 * 64 + kc];
  }

  for (int c = 0; c < nB; c++) {
    const int j0 = c * 128;
    __syncthreads();
#pragma unroll
    for (int c2 = 0; c2 < 2; c2++) {
      *(bf16x8*)&Ks[(c2 * 64 + kr) * LPK + kc] = kvp[c2];
      *(bf16x8*)&VTs[kr * LPV + c2 * 64 + kc] = vvp[c2];
    }
    __syncthreads();

    if (c + 1 < nB) {
      const int j1 = j0 + 128;
#pragma unroll
      for (int c2 = 0; c2 < 2; c2++) {
        kvp[c2] = *(const bf16x8*)&Kg[base + (size_t)(j1 + c2 * 64 + kr) * D_MODEL + kc];
        vvp[c2] = *(const bf16x8*)&Vt[baset + (size_t)kr * SEQ + j1 + c2 * 64 + kc];
      }
    }

    // kf hoisted once per chunk: shared by both q-set computes (LDS-pipe cut)
    bf16x8 kfh[4][2];
#pragma unroll
    for (int n = 0; n < 4; n++) {
      const int rk = g * 64 + n * 16 + lo16;
#pragma unroll
      for (int ks = 0; ks < 2; ks++)
        kfh[n][ks] = *(const bf16x8*)&Ks[rk * LPK + ks * 32 + quad * 8];
    }

    auto compute = [&](int q0s, const bf16x8* qf, floatx4* oacc, floatx4& lacc,
                       bool diag) {
      floatx4 sacc[4];
#pragma unroll
      for (int n = 0; n < 4; n++) sacc[n] = fz;
#pragma unroll
      for (int n = 0; n < 4; n++)
#pragma unroll
        for (int ks = 0; ks < 2; ks++)
          sacc[n] = __builtin_amdgcn_mfma_f32_16x16x32_bf16(kfh[n][ks], qf[ks], sacc[n], 0, 0, 0);

      // p = exp(s/8 - 12) = 2^(s*0.18033688 - 17.3123405); shift-invariant
      if (diag) {
        const int myq = q0s + w4 * 16 + lo16;
#pragma unroll
        for (int n = 0; n < 4; n++) {
          const int kvb = j0 + g * 64 + n * 16 + quad * 4;
          bf16x4 pk;
#pragma unroll
          for (int r = 0; r < 4; r++) {
            const float e = __builtin_amdgcn_exp2f(fmaf(sacc[n][r], 0.18033688f, -17.3123405f));
            pk[r] = (bf16)((kvb + r > myq) ? 0.f : e);
          }
          *(bf16x4*)&Ps[wid * 1152 + lo16 * LPP + n * 16 + quad * 4] = pk;
        }
      } else {
#pragma unroll
        for (int n = 0; n < 4; n++) {
          bf16x4 pk;
#pragma unroll
          for (int r = 0; r < 4; r++)
            pk[r] = (bf16)__builtin_amdgcn_exp2f(fmaf(sacc[n][r], 0.18033688f, -17.3123405f));
          *(bf16x4*)&Ps[wid * 1152 + lo16 * LPP + n * 16 + quad * 4] = pk;
        }
      }

      // O += P V; l += P 1  (in-wave DS ordering; Ps slice wave-private)
#pragma unroll
      for (int ks = 0; ks < 2; ks++) {
        bf16x8 pf = *(const bf16x8*)&Ps[wid * 1152 + lo16 * LPP + ks * 32 + quad * 8];
#pragma unroll
        for (int dt = 0; dt < 4; dt++) {
          bf16x8 vf = *(const bf16x8*)&VTs[(dt * 16 + lo16) * LPV + g * 64 + ks * 32 + quad * 8];
          oacc[dt] = __builtin_amdgcn_mfma_f32_16x16x32_bf16(pf, vf, oacc[dt], 0, 0, 0);
        }
        lacc = __builtin_amdgcn_mfma_f32_16x16x32_bf16(pf, onesf, lacc, 0, 0, 0);
      }
    };

    compute(qtB * 64, qfB, oB, lB, c == nB - 1);
    if (c < nA) compute(qtA * 64, qfA, oA, lA, c == nA - 1);
  }

  // epilogue: combine kv-half partials (additive; fixed shift). Es aliases
  // the staging LDS, so drain loop-phase LDS use first.
  __syncthreads();
  if (g == 1) {
    float* e = &Es[(w4 * 64 + lane) * 40];
#pragma unroll
    for (int dt = 0; dt < 4; dt++)
#pragma unroll
      for (int r = 0; r < 4; r++) e[dt * 4 + r] = oA[dt][r];
#pragma unroll
    for (int r = 0; r < 4; r++) e[16 + r] = lA[r];
#pragma unroll
    for (int dt = 0; dt < 4; dt++)
#pragma unroll
      for (int r = 0; r < 4; r++) e[20 + dt * 4 + r] = oB[dt][r];
#pragma unroll
    for (int r = 0; r < 4; r++) e[36 + r] = lB[r];
  }
  __syncthreads();
  if (g == 0) {
    const float* e = &Es[(w4 * 64 + lane) * 40];
#pragma unroll
    for (int dt = 0; dt < 4; dt++)
#pragma unroll
      for (int r = 0; r < 4; r++) { oA[dt][r] += e[dt * 4 + r]; oB[dt][r] += e[20 + dt * 4 + r]; }
#pragma unroll
    for (int r = 0; r < 4; r++) { lA[r] += e[16 + r]; lB[r] += e[36 + r]; }

    auto finish = [&](int q0s, floatx4* oacc, floatx4 lacc) {
#pragma unroll
      for (int r = 0; r < 4; r++) {
        const float inv = 1.0f / lacc[r];
        const int row = q0s + w4 * 16 + quad * 4 + r;
#pragma unroll
        for (int dt = 0; dt < 4; dt++)
          O[base + (size_t)row * D_MODEL + dt * 16 + lo16] = (bf16)(oacc[dt][r] * inv);
      }
    };
    finish(qtA * 64, oA, lA);
    finish(qtB * 64, oB, lB);
  }
}

extern "C" void kernel_launch(void* const* d_in, const int* in_sizes, int n_in,
                              void* d_out, int out_size, void* d_ws, size_t ws_size,
                              hipStream_t stream) {
  const float* X  = (const float*)d_in[0];
  const float* Wq = (const float*)d_in[1];
  const float* Wk = (const float*)d_in[2];
  const float* Wv = (const float*)d_in[3];
  const float* Wo = (const float*)d_in[4];
  float* out = (float*)d_out;

  bf16* cvt = (bf16*)d_ws;
  bf16* Xb  = cvt;
  bf16* Wqb = cvt + XELEMS;
  bf16* Wkb = Wqb + WELEMS;
  bf16* Wvb = Wkb + WELEMS;
  bf16* Wob = Wvb + WELEMS;
  bf16* Qb  = cvt + CVT_ELEMS;
  bf16* Kb  = Qb + XELEMS;
  bf16* Vtb = Kb + XELEMS;      // [B][H][DH][SEQ]
  bf16* Ob  = Vtb + XELEMS;

  dim3 blk(256);
  cvt_f32_bf16<<<dim3((u32)(CVT_ELEMS / (256 * 8))), blk, 0, stream>>>(
      X, Wq, Wk, Wv, Wo, cvt);
  gemm_qkv<<<dim3(8, 32, 3), blk, 0, stream>>>(Xb, Wqb, Wkb, Wvb, Qb, Kb, Vtb);
  attn_causal<<<dim3(16, NHEADS, BATCH), dim3(512), 0, stream>>>(Qb, Kb, Vtb, Ob);
  gemm_o<<<dim3(8, 64), blk, 0, stream>>>(Ob, Wob, out);
}